// Round 9
// baseline (149.211 us; speedup 1.0000x reference)
//
#include <hip/hip_runtime.h>
#include <stdint.h>

#define B_ 4
#define C_ 256
#define H_ 64
#define W_ 64
#define O_ 256
#define K_ 9
#define CK 2304     // K_*C_  (ck = k*256 + c, k-major)
#define HW 4096
#define NTOT 16384  // B_*HW

typedef __bf16 bf16x8 __attribute__((ext_vector_type(8)));
typedef __bf16 bf16x4 __attribute__((ext_vector_type(4)));
typedef float f32x4 __attribute__((ext_vector_type(4)));
typedef float f32x2 __attribute__((ext_vector_type(2)));
typedef f32x2 __attribute__((aligned(4))) f32x2u;

__device__ __forceinline__ uint16_t f2bf(float f) {
  uint32_t u = __builtin_bit_cast(uint32_t, f);
  return (uint16_t)((u + 0x7FFFu + ((u >> 16) & 1u)) >> 16);
}

__device__ __forceinline__ uint32_t pk_bf16(float a, float b) {
  uint16_t lo = __builtin_bit_cast(uint16_t, (__bf16)a);
  uint16_t hi = __builtin_bit_cast(uint16_t, (__bf16)b);
  return (uint32_t)lo | ((uint32_t)hi << 16);
}

// ======== kA v2 (R4/R7/R8-verified): weight converts | womb | zeros | xT transpose ====
__global__ void kA_prep(const float* __restrict__ weight, const float* __restrict__ w_om,
                        const float* __restrict__ x, uint16_t* __restrict__ wb,
                        uint16_t* __restrict__ womb, uint16_t* __restrict__ xT) {
  int bx = blockIdx.x;
  int t = threadIdx.x;
  if (bx < 256) {
    int o = bx, c = t;
    const float* wp = weight + (o * 256 + c) * 9;
#pragma unroll
    for (int k = 0; k < 9; ++k) wb[o * CK + k * 256 + c] = f2bf(wp[k]);
  } else if (bx < 283) {
    int j = bx - 256, c = t;  // j 0..26
    const float* wp = w_om + (j * 256 + c) * 9;
#pragma unroll
    for (int k = 0; k < 9; ++k) womb[j * CK + k * 256 + c] = f2bf(wp[k]);
  } else if (bx < 288) {
    int j = 27 + (bx - 283), c = t;  // zero rows 27..31 (row 31 = zrow)
#pragma unroll
    for (int k = 0; k < 9; ++k) womb[j * CK + k * 256 + c] = 0;
  } else {
    int bxl = bx - 288;
    int ct = bxl & 3;
    int hwt = (bxl >> 2) & 63;
    int b = bxl >> 8;
    int l = t & 63;
    int cq = t >> 6;

    __shared__ __align__(16) uint16_t tile[64 * 72];

    const float* xb = x + ((b * 256 + ct * 64) * HW) + hwt * 64;
#pragma unroll
    for (int i = 0; i < 16; ++i) {
      int c = cq * 16 + i;
      tile[l * 72 + c] = f2bf(xb[c * HW + l]);
    }
    __syncthreads();

    int hw = t >> 2;
    int c8 = (t & 3) * 8;
    uint16_t* dst = xT + ((size_t)b << 20) + (size_t)(hwt * 64 + hw) * 256 + ct * 64;
    *(uint4*)&dst[c8] = *(const uint4*)&tile[hw * 72 + c8];
    *(uint4*)&dst[c8 + 32] = *(const uint4*)&tile[hw * 72 + c8 + 32];
  }
}

// ======== k123 v3: 32n x 256O blocks, 512 of them, ~52 KB LDS => 2 blocks/CU ========
// Mechanism: inter-block overlap (m114) — while one block sits in its serial gather
// region / barrier drain, the co-resident block's waves issue MFMA. Prior intra-block
// overlap attempts (R1/R3/R5) all null; this uses the HW-proven cross-wave mechanism.
// Prologue: offset conv GEMM, waves = 2j x 2n x 2c-halves, LDS reduce over c-halves.
// Phase C: BK=32 As dbuf (m97 pattern), wave tile 32x32 (acc[2][2]), 4-row gather.
// Swizzles: As (32-wide rows) chunk ^ ((row>>1)&3), involution on stage-src + read;
// Bs (256-wide rows) chs=(kidx&24)|((kidx&7)^(row&7)) — identical to verified R7/R8.

#define NT 32  // n-rows per block

struct GatherState {
  float wa0[4], wb0[4], wa1[4], wb1[4];
  bf16x4 r00[4], r01[4], r10[4], r11[4];
};

__device__ __forceinline__ void gather_issue(GatherState& S, const uint16_t* __restrict__ xb,
                                             const float* pypx_l,  // LDS [3][9][NT]
                                             int kg, int rbase, int lane) {
#pragma unroll
  for (int j = 0; j < 4; ++j) {
    int nrow = rbase + j;
    float py = pypx_l[(0 * 9 + kg) * NT + nrow];
    float px = pypx_l[(1 * 9 + kg) * NT + nrow];
    float mk = pypx_l[(2 * 9 + kg) * NT + nrow];
    float fy0 = floorf(py), fx0 = floorf(px);
    float ly = py - fy0, lx = px - fx0;
    int y0 = (int)fy0, x0 = (int)fx0;
    bool vy0 = ((unsigned)y0 < 64u), vy1 = ((unsigned)(y0 + 1) < 64u);
    bool vx0 = ((unsigned)x0 < 64u), vx1 = ((unsigned)(x0 + 1) < 64u);
    float w00 = (vy0 && vx0) ? (1.f - ly) * (1.f - lx) * mk : 0.f;
    float w01 = (vy0 && vx1) ? (1.f - ly) * lx * mk : 0.f;
    float w10 = (vy1 && vx0) ? ly * (1.f - lx) * mk : 0.f;
    float w11 = (vy1 && vx1) ? ly * lx * mk : 0.f;
    bool sel0 = (x0 >= 63);
    bool sel1 = (x0 >= 0);
    S.wa0[j] = (sel0 ? 0.f : w00) + (sel1 ? 0.f : w01);
    S.wb0[j] = (sel0 ? w00 : 0.f) + (sel1 ? w01 : 0.f);
    S.wa1[j] = (sel0 ? 0.f : w10) + (sel1 ? 0.f : w11);
    S.wb1[j] = (sel0 ? w10 : 0.f) + (sel1 ? w11 : 0.f);
    int bx0 = min(max(x0, 0), 62);
    int a0 = min(max(y0, 0), 63) * 64 + bx0;
    int a1 = min(max(y0 + 1, 0), 63) * 64 + bx0;
    S.r00[j] = *(const bf16x4*)&xb[a0 * 256 + lane * 4];
    S.r01[j] = *(const bf16x4*)&xb[a0 * 256 + 256 + lane * 4];
    S.r10[j] = *(const bf16x4*)&xb[a1 * 256 + lane * 4];
    S.r11[j] = *(const bf16x4*)&xb[a1 * 256 + 256 + lane * 4];
  }
}

__device__ __forceinline__ void gather_finish(const GatherState& S, uint16_t* bslab,
                                              int rbase, int lane) {
#pragma unroll
  for (int j = 0; j < 4; ++j) {
    int nrow = rbase + j;
    float v[4];
#pragma unroll
    for (int i = 0; i < 4; ++i)
      v[i] = S.wa0[j] * (float)S.r00[j][i] + S.wb0[j] * (float)S.r01[j][i] +
             S.wa1[j] * (float)S.r10[j][i] + S.wb1[j] * (float)S.r11[j][i];
    uint2 pk;
    pk.x = pk_bf16(v[0], v[1]);
    pk.y = pk_bf16(v[2], v[3]);
    int chunk = lane >> 1;                               // 0..31 (8-elem chunks)
    int chs = (chunk & 24) | ((chunk & 7) ^ (nrow & 7)); // XOR swizzle, involution
    *(uint2*)&bslab[nrow * 256 + chs * 8 + (lane & 1) * 4] = pk;
  }
}

// stage wb[0..255][kbase..kbase+31] into a [256][32] As buffer (BK=32).
// swizzle: chunk p holds global chunk p ^ ((row>>1)&3); read applies same XOR.
__device__ __forceinline__ void stageA32(const uint16_t* __restrict__ wb, uint16_t* asbuf,
                                         int kbase, int t) {
#pragma unroll
  for (int i = 0; i < 2; ++i) {
    int slot = i * 512 + t;
    int row = slot >> 2, p = slot & 3;
    const uint16_t* src = wb + row * CK + kbase + ((p ^ ((row >> 1) & 3)) << 3);
    __builtin_amdgcn_global_load_lds(
        (const __attribute__((address_space(1))) uint32_t*)src,
        (__attribute__((address_space(3))) uint32_t*)&asbuf[row * 32 + p * 8], 16, 0, 0);
  }
}

__device__ __forceinline__ void mma32(const uint16_t* AsP, const uint16_t* BsP,
                                      f32x4 acc[2][2], int wm, int lr, int q, int s) {
  bf16x8 aF[2], bF[2];
#pragma unroll
  for (int i = 0; i < 2; ++i) {
    int arow = wm * 32 + i * 16 + lr;
    aF[i] = *(const bf16x8*)&AsP[arow * 32 + ((q ^ ((arow >> 1) & 3)) << 3)];
  }
#pragma unroll
  for (int j = 0; j < 2; ++j) {
    int brow = j * 16 + lr;
    int kidx = s * 4 + q;  // 0..31
    int chs = (kidx & 24) | ((kidx & 7) ^ (brow & 7));
    bF[j] = *(const bf16x8*)&BsP[brow * 256 + chs * 8];
  }
#pragma unroll
  for (int i = 0; i < 2; ++i)
#pragma unroll
    for (int j = 0; j < 2; ++j)
      acc[i][j] = __builtin_amdgcn_mfma_f32_16x16x32_bf16(aF[i], bF[j], acc[i][j], 0, 0, 0);
}

__global__ __launch_bounds__(512, 4) void k123(const uint16_t* __restrict__ wb,
                                               const uint16_t* __restrict__ womb,
                                               const uint16_t* __restrict__ xT,
                                               const float* __restrict__ b_om,
                                               const float* __restrict__ bias,
                                               float* __restrict__ out) {
  __shared__ __align__(16) uint16_t As[2][8192];  // 2 x 16 KB, [256][32] each
  __shared__ __align__(16) uint16_t Bs[8192];     // 16 KB, [32][256]
  __shared__ float pypx_l[3 * 9 * NT];            // 3456 B

  int t = threadIdx.x;
  int lane = t & 63;
  int wid = __builtin_amdgcn_readfirstlane(t >> 6);
  int lr = lane & 15, q = lane >> 4;
  int bx = blockIdx.x;
  int swz = (bx & 7) * 64 + (bx >> 3);  // bijective XCD swizzle (512 % 8 == 0)
  int n0 = swz * NT;
  int b = n0 >> 12;  // 32 | 4096 -> single batch per block
  int hw0 = n0 & 4095;
  const uint16_t* xb = xT + ((size_t)b << 20);

  // ====== prologue: offset conv GEMM (2j x 2n x 2c-half waves) -> pypx_l ======
  {
    uint16_t* Apro = (uint16_t*)As;  // 16 KB as [32 j][256 c]
    int ch = wid >> 2;        // c-half (K-split)
    int jh = (wid >> 1) & 1;  // j-tile (16 rows)
    int nh = wid & 1;         // n-tile (16 rows)
    const uint16_t* zrow = womb + 31 * CK;  // 2304 zeros
    f32x4 accp = {0.f, 0.f, 0.f, 0.f};

    for (int k = 0; k < 9; ++k) {
      int dy = k / 3 - 1, dx = k - (k / 3) * 3 - 1;
      // stage womb k-slice: 32x256 (1024 16B-chunks, 2/thread), coalesced
#pragma unroll
      for (int i = 0; i < 2; ++i) {
        int slot = i * 512 + t;
        int row = slot >> 5, c5 = slot & 31;
        int cs = (c5 & 24) | ((c5 & 7) ^ (row & 7));
        const uint16_t* src = womb + row * CK + k * 256 + cs * 8;
        __builtin_amdgcn_global_load_lds(
            (const __attribute__((address_space(1))) uint32_t*)src,
            (__attribute__((address_space(3))) uint32_t*)&Apro[row * 256 + c5 * 8], 16, 0, 0);
      }
      // stage identity-offset patch slab: 32n x 256c, zrow for OOB, coalesced
#pragma unroll
      for (int i = 0; i < 2; ++i) {
        int slot = i * 512 + t;
        int nrow = slot >> 5, c5 = slot & 31;
        int hw = (n0 + nrow) & 4095;
        int y = hw >> 6, xx = hw & 63;
        int ny = y + dy, nx = xx + dx;
        bool valid = ((unsigned)ny < 64u) && ((unsigned)nx < 64u);
        int row_g = (ny << 6) + nx;
        int cs = (c5 & 24) | ((c5 & 7) ^ (nrow & 7));
        const uint16_t* src = valid ? (xb + row_g * 256 + cs * 8) : (zrow + cs * 8);
        __builtin_amdgcn_global_load_lds(
            (const __attribute__((address_space(1))) uint32_t*)src,
            (__attribute__((address_space(3))) uint32_t*)&Bs[nrow * 256 + c5 * 8], 16, 0, 0);
      }
      __syncthreads();
      // 4 MFMA: j-tile jh x n-tile nh, c-half ch (128 c)
#pragma unroll
      for (int kt = 0; kt < 4; ++kt) {
        int kidx = ch * 16 + kt * 4 + q;
        int arow = jh * 16 + lr;
        int achs = (kidx & 24) | ((kidx & 7) ^ (arow & 7));
        bf16x8 aF = *(const bf16x8*)&Apro[arow * 256 + achs * 8];
        int brow = nh * 16 + lr;
        int bchs = (kidx & 24) | ((kidx & 7) ^ (brow & 7));
        bf16x8 bF = *(const bf16x8*)&Bs[brow * 256 + bchs * 8];
        accp = __builtin_amdgcn_mfma_f32_16x16x32_bf16(aF, bF, accp, 0, 0, 0);
      }
      __syncthreads();
    }

    // reduce c-halves via LDS (As area is free between barriers)
    float* red = (float*)As;  // [2][2][64][4] = 4 KB
    int rbase = ((jh * 2 + nh) * 64 + lane) * 4;
    if (ch == 1) {
#pragma unroll
      for (int r = 0; r < 4; ++r) red[rbase + r] = accp[r];
    }
    __syncthreads();
    if (ch == 0) {
      int nn = nh * 16 + lr;
      int hwp = (n0 + nn) & 4095;
      int yp = hwp >> 6, xp = hwp & 63;
#pragma unroll
      for (int r = 0; r < 4; ++r) {
        int j = jh * 16 + q * 4 + r;
        if (j < 27) {
          float v = accp[r] + red[rbase + r] + b_om[j];
          if (j < 18) {
            int k = j >> 1;
            if ((j & 1) == 0)
              pypx_l[(0 * 9 + k) * NT + nn] = (float)(yp - 1 + k / 3) + v;
            else
              pypx_l[(1 * 9 + k) * NT + nn] = (float)(xp - 1 + k % 3) + v;
          } else {
            pypx_l[(2 * 9 + (j - 18)) * NT + nn] = 1.f / (1.f + __expf(-v));
          }
        }
      }
    }
    __syncthreads();
  }

  // ============ phase C: fused gather + GEMM (BK=32, wave tile 32x32) ============
  f32x4 acc[2][2];
  const f32x4 zero = {0.f, 0.f, 0.f, 0.f};
#pragma unroll
  for (int i = 0; i < 2; ++i)
#pragma unroll
    for (int j = 0; j < 2; ++j) acc[i][j] = zero;

  int wm = wid;        // O-tile: rows wm*32 .. wm*32+31
  GatherState S;
  int wrow = wid * 4;  // this wave's 4 gather rows

  // prologue: gather k=0 slab into Bs; stage (k=0, seg 0) into As[0]
  gather_issue(S, xb, pypx_l, 0, wrow, lane);
  gather_finish(S, Bs, wrow, lane);
  stageA32(wb, As[0], 0, t);
  __syncthreads();

  for (int k = 0; k < 9; ++k) {
    for (int s = 0; s < 8; ++s) {
      // m97 pattern: stage next 32-K sub-slab into the OTHER As buffer, read current
      if (!(k == 8 && s == 7)) {
        int kb = (s == 7) ? (k + 1) * 256 : k * 256 + (s + 1) * 32;
        stageA32(wb, As[(s + 1) & 1], kb, t);
      }
      mma32(As[s & 1], Bs, acc, wm, lr, q, s);
      __syncthreads();
    }
    // isolated gather region for slab k+1 (writes after all reads, barriers around)
    if (k < 8) {
      gather_issue(S, xb, pypx_l, k + 1, wrow, lane);
      gather_finish(S, Bs, wrow, lane);
      __syncthreads();
    }
  }

  // epilogue (same fragment->C mapping as verified)
#pragma unroll
  for (int i = 0; i < 2; ++i) {
#pragma unroll
    for (int r = 0; r < 4; ++r) {
      int o = wm * 32 + i * 16 + q * 4 + r;
      float bv = bias[o];
      float* orow = out + (b * O_ + o) * HW + hw0;
#pragma unroll
      for (int j = 0; j < 2; ++j) orow[j * 16 + lr] = acc[i][j][r] + bv;
    }
  }
}

// ================= fallback path (small workspace): fp32 pipeline =============
__global__ void k0_wconv(const float* __restrict__ weight, uint16_t* __restrict__ wb) {
  int idx = blockIdx.x * 256 + threadIdx.x;
  if (idx >= O_ * CK) return;
  int o = idx / CK;
  int rem = idx - o * CK;
  int k = rem >> 8;
  int c = rem & 255;
  wb[idx] = f2bf(weight[(o * C_ + c) * K_ + k]);
}

__global__ void k1_offconv(const float* __restrict__ x, const float* __restrict__ w_om,
                           const float* __restrict__ b_om, float* __restrict__ pypxmk) {
  int bx = blockIdx.x;
  int jq = bx % 7;
  int h = (bx / 7) % H_;
  int b = bx / (7 * H_);
  int t = threadIdx.x;
  int w = t & 63;
  int cs = __builtin_amdgcn_readfirstlane(t >> 6);

  float acc[4] = {0.f, 0.f, 0.f, 0.f};
  const float* xb = x + (b * C_) * HW;

  for (int ci = 0; ci < 64; ++ci) {
    int c = cs * 64 + ci;
    const float* xr = xb + c * HW;
    float xv[3][3];
#pragma unroll
    for (int r = 0; r < 3; ++r) {
      int y = h - 1 + r;
      bool yv = ((unsigned)y < 64u);
#pragma unroll
      for (int dx = 0; dx < 3; ++dx) {
        int xx = w - 1 + dx;
        bool v = yv && ((unsigned)xx < 64u);
        xv[r][dx] = v ? xr[y * 64 + xx] : 0.f;
      }
    }
    const float* wp = w_om + ((jq * 4) * C_ + c) * 9;
#pragma unroll
    for (int jj = 0; jj < 4; ++jj) {
      int j = jq * 4 + jj;
      int jeff = (j < 27) ? jj : 0;
      const float* wj = wp + jeff * (C_ * 9);
      float a = 0.f;
#pragma unroll
      for (int r = 0; r < 3; ++r)
#pragma unroll
        for (int dx = 0; dx < 3; ++dx)
          a = fmaf(xv[r][dx], wj[r * 3 + dx], a);
      acc[jj] += a;
    }
  }

  __shared__ float red[4][4][64];
#pragma unroll
  for (int jj = 0; jj < 4; ++jj) red[cs][jj][w] = acc[jj];
  __syncthreads();

  int jj = t >> 6;
  int j = jq * 4 + jj;
  if (j < 27) {
    float s = red[0][jj][w] + red[1][jj][w] + red[2][jj][w] + red[3][jj][w] + b_om[j];
    float* pyA = pypxmk;
    float* pxA = pypxmk + 147456;
    float* mkA = pypxmk + 294912;
    if (j < 18) {
      int k = j >> 1;
      int off = (b * 9 + k) * HW + h * 64 + w;
      if ((j & 1) == 0)
        pyA[off] = (float)(h - 1 + k / 3) + s;
      else
        pxA[off] = (float)(w - 1 + k % 3) + s;
    } else {
      int k = j - 18;
      mkA[(b * 9 + k) * HW + h * 64 + w] = 1.f / (1.f + __expf(-s));
    }
  }
}

__global__ void k2_fb(const float* __restrict__ x, const float* __restrict__ pypxmk,
                      uint16_t* __restrict__ cols) {
  int bx = blockIdx.x;
  int cg2 = bx & 15;
  int h = (bx >> 4) & 63;
  int b = bx >> 10;
  int t = threadIdx.x;
  int w = t & 63;
  int g = t >> 6;

  const float* pyA = pypxmk;
  const float* pxA = pypxmk + 147456;
  const float* mkA = pypxmk + 294912;

  __shared__ uint16_t tile[64 * 146];
  const float* xb = x + b * C_ * HW;
  int cbase = cg2 * 16 + g * 4;

#pragma unroll
  for (int k = 0; k < 9; ++k) {
    int poff = (b * 9 + k) * HW + h * 64 + w;
    float py = pyA[poff];
    float px = pxA[poff];
    float mk = mkA[poff];
    float fy0 = floorf(py), fx0 = floorf(px);
    float ly = py - fy0, lx = px - fx0;
    int y0 = (int)fy0, x0 = (int)fx0;
    bool vy0 = ((unsigned)y0 < 64u), vy1 = ((unsigned)(y0 + 1) < 64u);
    bool vx0 = ((unsigned)x0 < 64u), vx1 = ((unsigned)(x0 + 1) < 64u);
    float w00 = (vy0 && vx0) ? (1.f - ly) * (1.f - lx) * mk : 0.f;
    float w01 = (vy0 && vx1) ? (1.f - ly) * lx * mk : 0.f;
    float w10 = (vy1 && vx0) ? ly * (1.f - lx) * mk : 0.f;
    float w11 = (vy1 && vx1) ? ly * lx * mk : 0.f;
    bool sel0 = (x0 >= 63);
    bool sel1 = (x0 >= 0);
    float wa0 = (sel0 ? 0.f : w00) + (sel1 ? 0.f : w01);
    float wb0 = (sel0 ? w00 : 0.f) + (sel1 ? w01 : 0.f);
    float wa1 = (sel0 ? 0.f : w10) + (sel1 ? 0.f : w11);
    float wb1 = (sel0 ? w10 : 0.f) + (sel1 ? w11 : 0.f);
    int bx0 = min(max(x0, 0), 62);
    int a0 = min(max(y0, 0), 63) * 64 + bx0;
    int a1 = min(max(y0 + 1, 0), 63) * 64 + bx0;

#pragma unroll
    for (int cp = 0; cp < 2; ++cp) {
      const float* xcA = xb + (cbase + cp * 2) * HW;
      const float* xcB = xcA + HW;
      f32x2 A0 = *(const f32x2u*)&xcA[a0];
      f32x2 A1 = *(const f32x2u*)&xcA[a1];
      f32x2 B0 = *(const f32x2u*)&xcB[a0];
      f32x2 B1 = *(const f32x2u*)&xcB[a1];
      float rA = wa0 * A0.x + wb0 * A0.y + wa1 * A1.x + wb1 * A1.y;
      float rB = wa0 * B0.x + wb0 * B0.y + wa1 * B1.x + wb1 * B1.y;
      *(uint32_t*)&tile[w * 146 + k * 16 + g * 4 + cp * 2] = pk_bf16(rA, rB);
    }
  }
  __syncthreads();

#pragma unroll
  for (int it = 0; it < 18; ++it) {
    int u = t + it * 256;
    int wu = u / 72;
    int rem = u - wu * 72;
    int k = rem >> 3;
    int cd = rem & 7;
    uint32_t val = *(const uint32_t*)&tile[wu * 146 + rem * 2];
    int n = b * HW + h * 64 + wu;
    int dst = n * CK + k * 256 + cg2 * 16 + cd * 2;
    *(uint32_t*)&cols[dst] = val;
  }
}

__global__ void k3_flex(const uint16_t* __restrict__ wb, const uint16_t* __restrict__ cols,
                        const float* __restrict__ bias, float* __restrict__ out) {
  int bx = blockIdx.x;
  int mt = bx & 1;
  int nt = bx >> 1;
  int o0 = mt * 128;
  int n0 = nt * 128;
  int t = threadIdx.x;
  int lane = t & 63;
  int wid = t >> 6;
  int wm = wid >> 1, wn = wid & 1;
  int lr = lane & 15, q = lane >> 4;

  __shared__ __align__(16) uint16_t As[128 * 32];
  __shared__ __align__(16) uint16_t Bs[128 * 32];

  f32x4 acc[4][4];
  const f32x4 zero = {0.f, 0.f, 0.f, 0.f};
#pragma unroll
  for (int i = 0; i < 4; ++i)
#pragma unroll
    for (int j = 0; j < 4; ++j) acc[i][j] = zero;

  int r0 = t >> 2;
  int koff = (t & 3) * 8;
  const uint16_t* gA = wb + (o0 + r0) * CK + koff;
  const uint16_t* gB = cols + (n0 + r0) * CK + koff;

  for (int kt = 0; kt < 72; ++kt) {
    int k0 = kt * 32;
    __builtin_amdgcn_global_load_lds(
        (const __attribute__((address_space(1))) uint32_t*)(gA + k0),
        (__attribute__((address_space(3))) uint32_t*)&As[t * 8], 16, 0, 0);
    __builtin_amdgcn_global_load_lds(
        (const __attribute__((address_space(1))) uint32_t*)(gA + 64 * CK + k0),
        (__attribute__((address_space(3))) uint32_t*)&As[2048 + t * 8], 16, 0, 0);
    __builtin_amdgcn_global_load_lds(
        (const __attribute__((address_space(1))) uint32_t*)(gB + k0),
        (__attribute__((address_space(3))) uint32_t*)&Bs[t * 8], 16, 0, 0);
    __builtin_amdgcn_global_load_lds(
        (const __attribute__((address_space(1))) uint32_t*)(gB + 64 * CK + k0),
        (__attribute__((address_space(3))) uint32_t*)&Bs[2048 + t * 8], 16, 0, 0);
    __syncthreads();

    bf16x8 aF[4], bF[4];
#pragma unroll
    for (int i = 0; i < 4; ++i)
      aF[i] = *(const bf16x8*)&As[(wm * 64 + i * 16 + lr) * 32 + q * 8];
#pragma unroll
    for (int j = 0; j < 4; ++j)
      bF[j] = *(const bf16x8*)&Bs[(wn * 64 + j * 16 + lr) * 32 + q * 8];
#pragma unroll
    for (int i = 0; i < 4; ++i)
#pragma unroll
      for (int j = 0; j < 4; ++j)
        acc[i][j] = __builtin_amdgcn_mfma_f32_16x16x32_bf16(aF[i], bF[j], acc[i][j], 0, 0, 0);
    __syncthreads();
  }

  int bb = n0 >> 12;
  int hw0 = n0 & 4095;
#pragma unroll
  for (int i = 0; i < 4; ++i) {
#pragma unroll
    for (int r = 0; r < 4; ++r) {
      int o = o0 + wm * 64 + i * 16 + q * 4 + r;
      float bv = bias[o];
      float* orow = out + (bb * O_ + o) * HW + hw0;
#pragma unroll
      for (int j = 0; j < 4; ++j) orow[wn * 64 + j * 16 + lr] = acc[i][j][r] + bv;
    }
  }
}

extern "C" void kernel_launch(void* const* d_in, const int* in_sizes, int n_in,
                              void* d_out, int out_size, void* d_ws, size_t ws_size,
                              hipStream_t stream) {
  const float* x = (const float*)d_in[0];
  const float* w_om = (const float*)d_in[1];
  const float* b_om = (const float*)d_in[2];
  const float* weight = (const float*)d_in[3];
  const float* bias = (const float*)d_in[4];
  float* out = (float*)d_out;

  char* ws = (char*)d_ws;
  uint16_t* wb = (uint16_t*)ws;                   // 1,179,648 B
  uint16_t* womb = (uint16_t*)(ws + 1179648);     // 147,456 B    -> 1,327,104
  uint16_t* xT = (uint16_t*)(ws + 1327104);       // 8,388,608 B  -> 9,715,712

  if (ws_size >= 11485184ull) {
    // 2-dispatch pipeline: prep -> fused {offset conv + gather + GEMM}, 2 blocks/CU
    hipLaunchKernelGGL(kA_prep, dim3(1312), dim3(256), 0, stream, weight, w_om, x, wb, womb, xT);
    hipLaunchKernelGGL(k123, dim3(512), dim3(512), 0, stream, wb, womb, xT, b_om, bias, out);
  } else {
    // fallback: fp32 pipeline + single-pass GEMM (needs 78.4 MB)
    float* pypx_fb = (float*)(ws + 1179648);
    uint16_t* colsf = (uint16_t*)(ws + 2949120);
    hipLaunchKernelGGL(k0_wconv, dim3(2304), dim3(256), 0, stream, weight, wb);
    hipLaunchKernelGGL(k1_offconv, dim3(4 * 64 * 7), dim3(256), 0, stream, x, w_om, b_om, pypx_fb);
    hipLaunchKernelGGL(k2_fb, dim3(4 * 64 * 16), dim3(256), 0, stream, x, pypx_fb, colsf);
    hipLaunchKernelGGL(k3_flex, dim3(256), dim3(256), 0, stream, wb, colsf, bias, out);
  }
}